// Round 5
// baseline (496.772 us; speedup 1.0000x reference)
//
#include <hip/hip_runtime.h>

#define T 256          // threads per block (4 waves)
#define NW (T / 64)
#define ROWLEN 16384
#define EPT4 (ROWLEN / T / 4)   // 16 float4 per thread
#define B1 4096        // 12-bit bins over ordered key
#define CAP 1024       // candidate capacity (expected ~98)

typedef float __attribute__((ext_vector_type(4))) f32x4;

// Order-preserving float->uint transform: u(a) < u(b)  <=>  a < b
__device__ __forceinline__ unsigned f2ord(float f) {
    unsigned b = __float_as_uint(f);
    return b ^ ((b & 0x80000000u) ? 0xFFFFFFFFu : 0x80000000u);
}
__device__ __forceinline__ float ord2f(unsigned u) {
    unsigned b = (u & 0x80000000u) ? (u ^ 0x80000000u) : ~u;
    return __uint_as_float(b);
}

// Find bin b* = max{b : S(b) >= k}, S(b) = sum_{d>=b} hist[d].
// Writes *sh_b = b*, *sh_k = k - S(b*+1). Ends with __syncthreads().
__device__ __forceinline__ void select_bin(const int* hist, int BINS, int k,
                                           int* waveSum, int* sh_b, int* sh_k) {
    const int tid  = threadIdx.x;
    const int lane = tid & 63;
    const int w    = tid >> 6;

    int bpt = (BINS + T - 1) / T;
    int lo  = tid * bpt; if (lo > BINS) lo = BINS;
    int hi  = lo + bpt;  if (hi > BINS) hi = BINS;

    int p = 0;
    for (int d = lo; d < hi; ++d) p += hist[d];

    // inclusive suffix scan within wave
    int v = p;
    #pragma unroll
    for (int off = 1; off < 64; off <<= 1) {
        int t2 = __shfl_down(v, off);
        if (lane + off < 64) v += t2;
    }
    if (lane == 0) waveSum[w] = v;
    __syncthreads();

    int carry = 0;
    #pragma unroll
    for (int w2 = 0; w2 < NW; ++w2) if (w2 > w) carry += waveSum[w2];

    int P  = v + carry;   // S(lo)
    int Pn = P - p;       // S(hi)
    if (P >= k && Pn < k) {   // unique crossing thread
        int running = Pn;
        for (int d = hi - 1; d >= lo; --d) {
            running += hist[d];
            if (running >= k) {
                *sh_b = d;
                *sh_k = k - (running - hist[d]);
                break;
            }
        }
    }
    __syncthreads();
}

__global__ __launch_bounds__(T, 8) void topk_relu_scatter(
        const float* __restrict__ x, const int* __restrict__ kptr,
        float* __restrict__ out) {
    __shared__ int hist[B1];          // 16 KB; upper half reused for candidates
    __shared__ int waveSum[NW];
    __shared__ int sh_b, sh_k, candCnt, sh_npos, sh_tmp;
    unsigned* candU = (unsigned*)&hist[2048];
    int*      candI = &hist[3072];

    const int tid = threadIdx.x;
    const int row = blockIdx.x;
    const float4* xrow = (const float4*)(x + (size_t)row * ROWLEN);
    float4*       orow = (float4*)(out + (size_t)row * ROWLEN);

    const int k = *kptr;   // 128, uniform

    // ---- zero hist ----
    #pragma unroll
    for (int i = 0; i < B1 / T; ++i) hist[tid + T * i] = 0;
    if (tid == 0) { candCnt = 0; sh_npos = 0; }
    __syncthreads();

    // ---- pass 1: histogram non-negative elements (top 12 bits) ----
    int npos = 0;
    #pragma unroll
    for (int j4 = 0; j4 < EPT4; ++j4) {
        float4 v = xrow[tid + T * j4];
        #pragma unroll
        for (int c = 0; c < 4; ++c) {
            unsigned u = f2ord((&v.x)[c]);
            if (u & 0x80000000u) {       // f >= +0
                ++npos;
                atomicAdd(&hist[u >> 20], 1);
            }
        }
    }
    #pragma unroll
    for (int off = 32; off >= 1; off >>= 1) npos += __shfl_down(npos, off);
    if ((tid & 63) == 0) atomicAdd(&sh_npos, npos);
    __syncthreads();

    if (sh_npos >= k) {
        select_bin(hist, B1, k, waveSum, &sh_b, &sh_k);
    } else {
        // rare: fewer than k non-negatives -> full histogram incl. negatives
        #pragma unroll
        for (int i = 0; i < B1 / T; ++i) hist[tid + T * i] = 0;
        __syncthreads();
        for (int j4 = 0; j4 < EPT4; ++j4) {
            float4 v = xrow[tid + T * j4];
            for (int c = 0; c < 4; ++c)
                atomicAdd(&hist[f2ord((&v.x)[c]) >> 20], 1);
        }
        __syncthreads();
        select_bin(hist, B1, k, waveSum, &sh_b, &sh_k);
    }
    const unsigned b1 = (unsigned)sh_b;
    const int      kk = sh_k;     // still needed within bin b1

    // ---- pass 2: re-read (L3-hot), dense write, collect candidates ----
    // hist[] is dead now; candU/candI alias its upper half.
    #pragma unroll
    for (int j4 = 0; j4 < EPT4; ++j4) {
        float4 v = xrow[tid + T * j4];
        float4 o;
        #pragma unroll
        for (int c = 0; c < 4; ++c) {
            float f = (&v.x)[c];
            unsigned u = f2ord(f);
            unsigned bin = u >> 20;
            (&o.x)[c] = (bin > b1 && f > 0.0f) ? f : 0.0f;
            if (bin == b1) {
                int p = atomicAdd(&candCnt, 1);
                if (p < CAP) { candU[p] = u; candI[p] = 4 * (tid + T * j4) + c; }
            }
        }
        __builtin_nontemporal_store(*(const f32x4*)&o, (f32x4*)&orow[tid + T * j4]);
    }
    __syncthreads();
    const int m = candCnt;

    if (m <= CAP) {
        // ---- stable rank among candidates; accept top kk; fix-up writes ----
        for (int i = tid; i < m; i += T) {
            unsigned ui = candU[i]; int xi = candI[i];
            int rank = 0;
            for (int j = 0; j < m; ++j) {
                unsigned uj = candU[j];
                rank += (uj > ui) || (uj == ui && candI[j] < xi);
            }
            if (rank < kk) {
                float f = ord2f(ui);
                if (f > 0.0f) out[(size_t)row * ROWLEN + xi] = f;
            }
        }
    } else {
        // ---- adversarial fallback: refine threshold to full 32 bits ----
        unsigned pref = b1; int plen = 12; int kk2 = kk;
        while (plen < 32) {
            int bits = (32 - plen >= 8) ? 8 : (32 - plen);
            int nb = 1 << bits;
            for (int i = tid; i < nb; i += T) hist[i] = 0;
            __syncthreads();
            for (int j4 = 0; j4 < EPT4; ++j4) {
                float4 v = xrow[tid + T * j4];
                for (int c = 0; c < 4; ++c) {
                    unsigned u = f2ord((&v.x)[c]);
                    if ((u >> (32 - plen)) == pref)
                        atomicAdd(&hist[(u >> (32 - plen - bits)) & (nb - 1)], 1);
                }
            }
            __syncthreads();
            select_bin(hist, nb, kk2, waveSum, &sh_b, &sh_k);
            pref = (pref << bits) | (unsigned)sh_b;
            kk2 = sh_k;
            plen += bits;
        }
        const unsigned ustar = pref;
        const int t_eq = kk2;

        // count equals
        if (tid == 0) sh_tmp = 0;
        __syncthreads();
        {
            int c2 = 0;
            for (int j4 = 0; j4 < EPT4; ++j4) {
                float4 v = xrow[tid + T * j4];
                for (int c = 0; c < 4; ++c) c2 += (f2ord((&v.x)[c]) == ustar);
            }
            if (c2) atomicAdd(&sh_tmp, c2);
        }
        __syncthreads();
        const int meq = sh_tmp;

        int idxcut;
        if (t_eq >= meq) {
            idxcut = ROWLEN;
        } else {
            int lo = 0, hi = ROWLEN - 1;
            while (lo < hi) {
                int mid = (lo + hi) >> 1;
                __syncthreads();
                if (tid == 0) sh_tmp = 0;
                __syncthreads();
                int c2 = 0;
                for (int j4 = 0; j4 < EPT4; ++j4) {
                    float4 v = xrow[tid + T * j4];
                    for (int c = 0; c < 4; ++c) {
                        int idx = 4 * (tid + T * j4) + c;
                        c2 += (f2ord((&v.x)[c]) == ustar && idx <= mid);
                    }
                }
                if (c2) atomicAdd(&sh_tmp, c2);
                __syncthreads();
                if (sh_tmp >= t_eq) hi = mid; else lo = mid + 1;
            }
            idxcut = lo;
        }

        // fix-up pass over the threshold bin
        for (int j4 = 0; j4 < EPT4; ++j4) {
            float4 v = xrow[tid + T * j4];
            for (int c = 0; c < 4; ++c) {
                float f = (&v.x)[c];
                unsigned u = f2ord(f);
                int idx = 4 * (tid + T * j4) + c;
                bool sel = ((u >> 20) == b1 && u > ustar) ||
                           (u == ustar && idx <= idxcut);
                if (sel && f > 0.0f) out[(size_t)row * ROWLEN + idx] = f;
            }
        }
    }
}

extern "C" void kernel_launch(void* const* d_in, const int* in_sizes, int n_in,
                              void* d_out, int out_size, void* d_ws, size_t ws_size,
                              hipStream_t stream) {
    const float* x    = (const float*)d_in[0];
    const int*   kptr = (const int*)d_in[1];
    float*       out  = (float*)d_out;
    int rows = in_sizes[0] / ROWLEN;   // 4096
    topk_relu_scatter<<<rows, T, 0, stream>>>(x, kptr, out);
}

// Round 8
// 465.422 us; speedup vs baseline: 1.0674x; 1.0674x over previous
//
#include <hip/hip_runtime.h>

#define T 256          // threads per block (4 waves)
#define NW (T / 64)
#define ROWLEN 16384
#define EPT4 (ROWLEN / T / 4)   // 16 float4 per thread
#define CAP 1024       // candidate capacity (expected ~373 for this input)
#define THRESH 2.0f    // fast-path filter; exactness guarded by n>=k check

// Order-preserving float->uint transform (fallback path only; fast path uses
// raw positive-float bit compares, which are monotone)
__device__ __forceinline__ unsigned f2ord(float f) {
    unsigned b = __float_as_uint(f);
    return b ^ ((b & 0x80000000u) ? 0xFFFFFFFFu : 0x80000000u);
}

// Find bin b* = max{b : S(b) >= k}, S(b) = sum_{d>=b} hist[d].
// Writes *sh_b = b*, *sh_k = k - S(b*+1). Ends with __syncthreads().
__device__ __forceinline__ void select_bin(const int* hist, int BINS, int k,
                                           int* waveSum, int* sh_b, int* sh_k) {
    const int tid  = threadIdx.x;
    const int lane = tid & 63;
    const int w    = tid >> 6;

    int bpt = (BINS + T - 1) / T;
    int lo  = tid * bpt; if (lo > BINS) lo = BINS;
    int hi  = lo + bpt;  if (hi > BINS) hi = BINS;

    int p = 0;
    for (int d = lo; d < hi; ++d) p += hist[d];

    // inclusive suffix scan within wave
    int v = p;
    #pragma unroll
    for (int off = 1; off < 64; off <<= 1) {
        int t2 = __shfl_down(v, off);
        if (lane + off < 64) v += t2;
    }
    if (lane == 0) waveSum[w] = v;
    __syncthreads();

    int carry = 0;
    #pragma unroll
    for (int w2 = 0; w2 < NW; ++w2) if (w2 > w) carry += waveSum[w2];

    int P  = v + carry;   // S(lo)
    int Pn = P - p;       // S(hi)
    if (P >= k && Pn < k) {   // unique crossing thread
        int running = Pn;
        for (int d = hi - 1; d >= lo; --d) {
            running += hist[d];
            if (running >= k) {
                *sh_b = d;
                *sh_k = k - (running - hist[d]);
                break;
            }
        }
    }
    __syncthreads();
}

__global__ __launch_bounds__(T, 8) void topk_relu_scatter(
        const float* __restrict__ x, const int* __restrict__ kptr,
        float* __restrict__ out) {
    __shared__ unsigned candU[CAP];   // 4 KB
    __shared__ int      candI[CAP];   // 4 KB
    __shared__ int      h256[256];    // 1 KB
    __shared__ int      waveSum[NW];
    __shared__ int      sh_b, sh_k, candCnt, sh_tmp;

    const int tid  = threadIdx.x;
    const int lane = tid & 63;
    const int row  = blockIdx.x;
    const float4* xrow = (const float4*)(x + (size_t)row * ROWLEN);
    float4*       orow = (float4*)(out + (size_t)row * ROWLEN);
    const int k = *kptr;   // 128, uniform

    if (tid == 0) candCnt = 0;
    __syncthreads();

    // ======== pass 1: single stream — zero-fill output, collect tail ========
    const float4 z4 = make_float4(0.f, 0.f, 0.f, 0.f);
    #pragma unroll
    for (int j4 = 0; j4 < EPT4; ++j4) {
        float4 v = xrow[tid + T * j4];
        orow[tid + T * j4] = z4;           // independent of load; issues early
        #pragma unroll
        for (int c = 0; c < 4; ++c) {
            float f = (&v.x)[c];
            bool cand = (f >= THRESH);
            unsigned long long mask = __ballot(cand);
            if (cand) {
                // one LDS atomic per wave-iteration: first active lane reserves
                int before = __popcll(mask & ((1ull << lane) - 1ull));
                int first  = __ffsll((unsigned long long)mask) - 1;
                int base = 0;
                if (lane == first) base = atomicAdd(&candCnt, __popcll(mask));
                base = __shfl(base, first);
                int p = base + before;
                if (p < CAP) {
                    candU[p] = __float_as_uint(f);      // positive: bits monotone
                    candI[p] = 4 * (tid + T * j4) + c;
                }
            }
        }
    }
    __syncthreads();
    const int n = candCnt;   // uniform

    if (n >= k && n <= CAP) {
        // ======== fast path: exact select among n candidates in LDS ========
        int kk = k;
        unsigned pref = 0; int plen = 0;
        #pragma unroll
        for (int p = 3; p >= 0; --p) {           // byte-radix, high to low
            h256[tid & 255] = 0;                  // T==256: one bin each
            __syncthreads();
            for (int i = tid; i < n; i += T) {
                unsigned u = candU[i];
                bool match = (plen == 0) || ((u >> (32 - plen)) == pref);
                if (match) atomicAdd(&h256[(u >> (8 * p)) & 0xFFu], 1);
            }
            __syncthreads();
            select_bin(h256, 256, kk, waveSum, &sh_b, &sh_k);
            pref = (pref << 8) | (unsigned)sh_b;
            kk   = sh_k;
            plen += 8;
        }
        const unsigned ustar = pref;
        const int t_eq = kk;      // equals to accept, lowest index first

        // count equals
        if (tid == 0) sh_tmp = 0;
        __syncthreads();
        {
            int c2 = 0;
            for (int i = tid; i < n; i += T) c2 += (candU[i] == ustar);
            if (c2) atomicAdd(&sh_tmp, c2);
        }
        __syncthreads();
        const int meq = sh_tmp;

        int idxcut;
        if (t_eq >= meq) {
            idxcut = ROWLEN;       // accept all equals (overwhelmingly common)
        } else {
            int lo2 = 0, hi2 = ROWLEN - 1;       // rare: duplicates at the cut
            while (lo2 < hi2) {
                int mid = (lo2 + hi2) >> 1;
                __syncthreads();
                if (tid == 0) sh_tmp = 0;
                __syncthreads();
                int c2 = 0;
                for (int i = tid; i < n; i += T)
                    c2 += (candU[i] == ustar && candI[i] <= mid);
                if (c2) atomicAdd(&sh_tmp, c2);
                __syncthreads();
                if (sh_tmp >= t_eq) hi2 = mid; else lo2 = mid + 1;
            }
            idxcut = lo2;
        }

        // fix-up: ~k scattered stores; lines are L2-hot from the zero fill
        for (int i = tid; i < n; i += T) {
            unsigned u = candU[i]; int xi = candI[i];
            bool sel = (u > ustar) || (u == ustar && candI[i] <= idxcut);
            if (sel) out[(size_t)row * ROWLEN + xi] = __uint_as_float(u); // >=2>0
        }
    } else {
        // ======== exact fallback (never taken for benchmark data) ========
        // 4-pass byte-radix over the full row on ordered keys, then rewrite.
        int kk = k;
        unsigned pref = 0; int plen = 0;
        for (int p = 3; p >= 0; --p) {
            h256[tid & 255] = 0;
            __syncthreads();
            for (int j4 = 0; j4 < EPT4; ++j4) {
                float4 v = xrow[tid + T * j4];
                for (int c = 0; c < 4; ++c) {
                    unsigned u = f2ord((&v.x)[c]);
                    bool match = (plen == 0) || ((u >> (32 - plen)) == pref);
                    if (match) atomicAdd(&h256[(u >> (8 * p)) & 0xFFu], 1);
                }
            }
            __syncthreads();
            select_bin(h256, 256, kk, waveSum, &sh_b, &sh_k);
            pref = (pref << 8) | (unsigned)sh_b;
            kk   = sh_k;
            plen += 8;
        }
        const unsigned ustar = pref;
        const int t_eq = kk;

        if (tid == 0) sh_tmp = 0;
        __syncthreads();
        {
            int c2 = 0;
            for (int j4 = 0; j4 < EPT4; ++j4) {
                float4 v = xrow[tid + T * j4];
                for (int c = 0; c < 4; ++c) c2 += (f2ord((&v.x)[c]) == ustar);
            }
            if (c2) atomicAdd(&sh_tmp, c2);
        }
        __syncthreads();
        const int meq = sh_tmp;

        int idxcut;
        if (t_eq >= meq) {
            idxcut = ROWLEN;
        } else {
            int lo2 = 0, hi2 = ROWLEN - 1;
            while (lo2 < hi2) {
                int mid = (lo2 + hi2) >> 1;
                __syncthreads();
                if (tid == 0) sh_tmp = 0;
                __syncthreads();
                int c2 = 0;
                for (int j4 = 0; j4 < EPT4; ++j4) {
                    float4 v = xrow[tid + T * j4];
                    for (int c = 0; c < 4; ++c) {
                        int idx = 4 * (tid + T * j4) + c;
                        c2 += (f2ord((&v.x)[c]) == ustar && idx <= mid);
                    }
                }
                if (c2) atomicAdd(&sh_tmp, c2);
                __syncthreads();
                if (sh_tmp >= t_eq) hi2 = mid; else lo2 = mid + 1;
            }
            idxcut = lo2;
        }

        // dense exact rewrite (overwrites the zero fill)
        for (int j4 = 0; j4 < EPT4; ++j4) {
            float4 v = xrow[tid + T * j4];
            float4 o;
            for (int c = 0; c < 4; ++c) {
                float f = (&v.x)[c];
                unsigned u = f2ord(f);
                int idx = 4 * (tid + T * j4) + c;
                bool sel = (u > ustar) || (u == ustar && idx <= idxcut);
                (&o.x)[c] = (sel && f > 0.0f) ? f : 0.0f;
            }
            orow[tid + T * j4] = o;
        }
    }
}

extern "C" void kernel_launch(void* const* d_in, const int* in_sizes, int n_in,
                              void* d_out, int out_size, void* d_ws, size_t ws_size,
                              hipStream_t stream) {
    const float* x    = (const float*)d_in[0];
    const int*   kptr = (const int*)d_in[1];
    float*       out  = (float*)d_out;
    int rows = in_sizes[0] / ROWLEN;   // 4096
    topk_relu_scatter<<<rows, T, 0, stream>>>(x, kptr, out);
}